// Round 1
// baseline (214.643 us; speedup 1.0000x reference)
//
#include <hip/hip_runtime.h>

#define NSET 48
#define NITEM 128
#define DIM 256
#define HEADS 4
#define NROWS (NSET * NITEM)   // 6144 rows per source

typedef _Float16 f16;
typedef _Float16 f16x8 __attribute__((ext_vector_type(8)));
typedef _Float16 f16x4 __attribute__((ext_vector_type(4)));
typedef float    f32x4 __attribute__((ext_vector_type(4)));

// ---- workspace layout (bytes) ----
// XYN  f16[12288][256] @ 0         normalized rows (x rows 0..6143, y rows 6144..12287)
// XYH  f16[12288][256] @ 0x600000  raw fp16 rows
// WT   f16[256][256]   @ 0xC00000  W transposed: WT[c][d] = W[d][c]
// LXY  f16[12288][256] @ 0xC20000  projected rows (head h = cols h*64..h*64+63)
static constexpr size_t OFF_XYH = 6291456;
static constexpr size_t OFF_WT  = 12582912;
static constexpr size_t OFF_LXY = 12713984;

// ---------------- prep: W transpose + fp16 ----------------
__global__ __launch_bounds__(256) void k_wt(const float* __restrict__ W,
                                            f16* __restrict__ WT) {
  int c = blockIdx.x, d = threadIdx.x;
  WT[c * DIM + d] = (f16)W[d * DIM + c];
}

// ---------------- prep: row l2-normalize + fp16 casts ----------------
__global__ __launch_bounds__(256) void k_norm(const float* __restrict__ x,
                                              const float* __restrict__ y,
                                              f16* __restrict__ XYN,
                                              f16* __restrict__ XYH) {
  int row  = blockIdx.x * 4 + (threadIdx.x >> 6);   // one wave per 256-elem row
  int lane = threadIdx.x & 63;
  const float* src = (row < NROWS) ? (x + (size_t)row * DIM)
                                   : (y + (size_t)(row - NROWS) * DIM);
  float4 v = *(const float4*)(src + lane * 4);
  float ss = v.x * v.x + v.y * v.y + v.z * v.z + v.w * v.w;
  #pragma unroll
  for (int off = 32; off >= 1; off >>= 1) ss += __shfl_xor(ss, off);
  float rn = 1.0f / sqrtf(fmaxf(ss, 1e-12f));       // tf.nn.l2_normalize semantics
  f16x4 hn = { (f16)(v.x * rn), (f16)(v.y * rn), (f16)(v.z * rn), (f16)(v.w * rn) };
  f16x4 hr = { (f16)v.x, (f16)v.y, (f16)v.z, (f16)v.w };
  *(f16x4*)(XYN + (size_t)row * DIM + lane * 4) = hn;
  *(f16x4*)(XYH + (size_t)row * DIM + lane * 4) = hr;
}

// ---------------- shared helpers ----------------
// Stage two 128x256 fp16 tiles (A -> smem[0..64K), B -> smem[64K..128K)).
// Rows are 512B; LDS byte within row is XOR-swizzled by ((row&15)<<4) so that
// ds_read_b128 fragment reads (16 consecutive rows, same 16B column) spread
// evenly over all banks. Global loads stay linear/coalesced; swizzle applied
// on the LDS write address (bijective involution within each 512B row).
__device__ __forceinline__ void stage_tile(const f16* __restrict__ gA,
                                           const f16* __restrict__ gB,
                                           char* smem, int tid) {
  const int w = tid >> 6, lane = tid & 63;
  const char* gsrc = (const char*)((w < 2) ? gA : gB);   // waves 0,1 -> A; 2,3 -> B
  char* lhalf = smem + ((w >= 2) ? 65536 : 0);
  const int hb = (w & 1) * 32768;                        // 32KB per wave
  #pragma unroll
  for (int qq = 0; qq < 4; ++qq) {
    int4 v[8];
    #pragma unroll
    for (int q = 0; q < 8; ++q) {
      int Lh = hb + (qq * 8 + q) * 1024 + lane * 16;     // linear byte offset
      v[q] = *(const int4*)(gsrc + Lh);
    }
    #pragma unroll
    for (int q = 0; q < 8; ++q) {
      int Lh  = hb + (qq * 8 + q) * 1024 + lane * 16;
      int row = Lh >> 9, cb = Lh & 511;
      *(int4*)(lhalf + row * 512 + (cb ^ ((row & 15) << 4))) = v[q];
    }
  }
}

// Fragment read for mfma_16x16x32: lane l -> row rowbase+(l&15),
// k bytes k0*2 + (l>>4)*16, 8 contiguous halves. rowbase%16==0 so row&15==l&15.
__device__ __forceinline__ f16x8 ldsfrag(const char* half_base, int rowbase,
                                         int k0, int lane) {
  int row = rowbase + (lane & 15);
  int kb  = (k0 << 1) + ((lane >> 4) << 4);
  return *(const f16x8*)(half_base + row * 512 + (kb ^ ((row & 15) << 4)));
}

// ---------------- prep: projection GEMM  proj[R][c] = XYH[R][:] . WT[c][:] ----------------
__global__ __launch_bounds__(256) void k_proj(const f16* __restrict__ XYH,
                                              const f16* __restrict__ WT,
                                              f16* __restrict__ LXY) {
  extern __shared__ char smem[];
  const int bid = blockIdx.x, rt = bid >> 1, ct = bid & 1;   // 96 row-tiles x 2 col-tiles
  const int tid = threadIdx.x, w = tid >> 6, lane = tid & 63;
  const int wr = (w >> 1) * 64, wc = (w & 1) * 64;
  stage_tile(XYH + (size_t)rt * 128 * DIM, WT + (size_t)ct * 128 * DIM, smem, tid);
  __syncthreads();
  f32x4 acc[4][4] = {};
  #pragma unroll
  for (int k0 = 0; k0 < DIM; k0 += 32) {
    f16x8 a[4], b[4];
    #pragma unroll
    for (int m = 0; m < 4; ++m) a[m] = ldsfrag(smem, wr + m * 16, k0, lane);
    #pragma unroll
    for (int n = 0; n < 4; ++n) b[n] = ldsfrag(smem + 65536, wc + n * 16, k0, lane);
    #pragma unroll
    for (int m = 0; m < 4; ++m)
      #pragma unroll
      for (int n = 0; n < 4; ++n)
        acc[m][n] = __builtin_amdgcn_mfma_f32_16x16x32_f16(a[m], b[n], acc[m][n], 0, 0, 0);
  }
  const int ci = (lane >> 4) * 4, cj = lane & 15;  // C/D: col=lane&15, row=(lane>>4)*4+r
  #pragma unroll
  for (int m = 0; m < 4; ++m)
    #pragma unroll
    for (int n = 0; n < 4; ++n)
      #pragma unroll
      for (int r = 0; r < 4; ++r) {
        int R = rt * 128 + wr + m * 16 + ci + r;
        int c = ct * 128 + wc + n * 16 + cj;
        LXY[(size_t)R * DIM + c] = (f16)acc[m][n][r];
      }
}

// ---------------- main: per (y,x) pair -> cos_sim tile + score ----------------
__global__ __launch_bounds__(256) void k_main(const f16* __restrict__ XYN,
                                              const f16* __restrict__ LXY,
                                              const float* __restrict__ nItem,
                                              const float* __restrict__ w2,
                                              float* __restrict__ out0,
                                              float* __restrict__ out1) {
  extern __shared__ char smem[];
  __shared__ float red[4][4];
  const int bid = blockIdx.x;
  const int ys = bid / NSET, xs = bid % NSET;   // x fastest: y-set data stays hot in L2
  const int tid = threadIdx.x, w = tid >> 6, lane = tid & 63;
  const int wr = (w >> 1) * 64, wc = (w & 1) * 64;
  const int ci = (lane >> 4) * 4, cj = lane & 15;

  // ---- phase 1: cos_sim[y, x, i, j] = xn[x,i,:] . yn[y,j,:] ----
  stage_tile(XYN + (size_t)xs * NITEM * DIM,
             XYN + (size_t)(NROWS + ys * NITEM) * DIM, smem, tid);
  __syncthreads();
  {
    f32x4 acc[4][4] = {};
    #pragma unroll
    for (int k0 = 0; k0 < DIM; k0 += 32) {
      f16x8 a[4], b[4];
      #pragma unroll
      for (int m = 0; m < 4; ++m) a[m] = ldsfrag(smem, wr + m * 16, k0, lane);
      #pragma unroll
      for (int n = 0; n < 4; ++n) b[n] = ldsfrag(smem + 65536, wc + n * 16, k0, lane);
      #pragma unroll
      for (int m = 0; m < 4; ++m)
        #pragma unroll
        for (int n = 0; n < 4; ++n)
          acc[m][n] = __builtin_amdgcn_mfma_f32_16x16x32_f16(a[m], b[n], acc[m][n], 0, 0, 0);
    }
    float* base = out0 + (size_t)(ys * NSET + xs) * NITEM * NITEM;
    #pragma unroll
    for (int m = 0; m < 4; ++m)
      #pragma unroll
      for (int n = 0; n < 4; ++n)
        #pragma unroll
        for (int r = 0; r < 4; ++r)
          base[(size_t)(wr + m * 16 + ci + r) * NITEM + (wc + n * 16 + cj)] = acc[m][n][r];
  }
  __syncthreads();

  // ---- phase 2: scores. s[h] = sum_ij relu(lx[i,h*64:].ly[j,h*64:]) ----
  stage_tile(LXY + (size_t)xs * NITEM * DIM,
             LXY + (size_t)(NROWS + ys * NITEM) * DIM, smem, tid);
  __syncthreads();
  float rsum[HEADS];
  #pragma unroll
  for (int h = 0; h < HEADS; ++h) {
    f32x4 acc[4][4] = {};
    #pragma unroll
    for (int kk = 0; kk < 2; ++kk) {             // K=64 per head, relu AFTER full K
      int k0 = h * 64 + kk * 32;
      f16x8 a[4], b[4];
      #pragma unroll
      for (int m = 0; m < 4; ++m) a[m] = ldsfrag(smem, wr + m * 16, k0, lane);
      #pragma unroll
      for (int n = 0; n < 4; ++n) b[n] = ldsfrag(smem + 65536, wc + n * 16, k0, lane);
      #pragma unroll
      for (int m = 0; m < 4; ++m)
        #pragma unroll
        for (int n = 0; n < 4; ++n)
          acc[m][n] = __builtin_amdgcn_mfma_f32_16x16x32_f16(a[m], b[n], acc[m][n], 0, 0, 0);
    }
    float s = 0.f;
    #pragma unroll
    for (int m = 0; m < 4; ++m)
      #pragma unroll
      for (int n = 0; n < 4; ++n)
        #pragma unroll
        for (int r = 0; r < 4; ++r) s += fmaxf(acc[m][n][r], 0.f);
    rsum[h] = s;
  }
  #pragma unroll
  for (int off = 32; off >= 1; off >>= 1)
    #pragma unroll
    for (int h = 0; h < HEADS; ++h) rsum[h] += __shfl_xor(rsum[h], off);
  if (lane == 0) {
    #pragma unroll
    for (int h = 0; h < HEADS; ++h) red[w][h] = rsum[h];
  }
  __syncthreads();
  if (tid == 0) {
    // relu(S/8) summed == (sum relu(S))/8 ; then / nItem[x] / nItem[y]; then @ w2
    float inv = 1.0f / (8.0f * nItem[xs] * nItem[ys]);
    float sc = 0.f;
    #pragma unroll
    for (int h = 0; h < HEADS; ++h)
      sc += (red[0][h] + red[1][h] + red[2][h] + red[3][h]) * inv * w2[h];
    out1[ys * NSET + xs] = sc;
  }
}

// ---------------- launch ----------------
extern "C" void kernel_launch(void* const* d_in, const int* in_sizes, int n_in,
                              void* d_out, int out_size, void* d_ws, size_t ws_size,
                              hipStream_t stream) {
  const float* x     = (const float*)d_in[0];
  const float* y     = (const float*)d_in[1];
  const float* nItem = (const float*)d_in[2];
  const float* W     = (const float*)d_in[3];
  const float* w2    = (const float*)d_in[4];
  float* out0 = (float*)d_out;
  float* out1 = out0 + (size_t)NSET * NSET * NITEM * NITEM;

  char* ws = (char*)d_ws;
  f16* XYN = (f16*)ws;
  f16* XYH = (f16*)(ws + OFF_XYH);
  f16* WT  = (f16*)(ws + OFF_WT);
  f16* LXY = (f16*)(ws + OFF_LXY);

  hipFuncSetAttribute((const void*)k_proj, hipFuncAttributeMaxDynamicSharedMemorySize, 131072);
  hipFuncSetAttribute((const void*)k_main, hipFuncAttributeMaxDynamicSharedMemorySize, 131072);

  k_wt<<<256, 256, 0, stream>>>(W, WT);
  k_norm<<<(2 * NROWS) / 4, 256, 0, stream>>>(x, y, XYN, XYH);
  k_proj<<<192, 256, 131072, stream>>>(XYH, WT, LXY);
  k_main<<<NSET * NSET, 256, 131072, stream>>>(XYN, LXY, nItem, w2, out0, out1);
}